// Round 17
// baseline (655.780 us; speedup 1.0000x reference)
//
#include <hip/hip_runtime.h>
#include <hip/hip_bf16.h>
#include <stdint.h>

#define M_DIM 4096
#define N_DIM 11008
#define K_DIM 4096
#define KP    (K_DIM / 2)   // packed int32s per weight row

typedef __attribute__((ext_vector_type(4))) int i32x4;

#define AS1 __attribute__((address_space(1)))
#define AS3 __attribute__((address_space(3)))

// ---------------- Fused pre-pass: quant_x (blocks 0..4095) + pack_q (blocks 4096..8191) ----------------
__global__ __launch_bounds__(256) void prep(const float* __restrict__ x,
                                            const int* __restrict__ pw,
                                            signed char* __restrict__ xq,
                                            signed char* __restrict__ wq,
                                            float* __restrict__ r,
                                            float* __restrict__ sx) {
  const int b = blockIdx.x;
  const int t = threadIdx.x;
  if (b < 4096) {
    // --- per-row quantize x -> i8, emit r[b]=sum(x), sx[b]=scale ---
    const int row = b;
    const int lane = t & 63, wid = t >> 6;
    const float4* x4 = (const float4*)(x + (size_t)row * K_DIM);
    float4 v[4];
    float am = 0.0f, sm = 0.0f;
#pragma unroll
    for (int i = 0; i < 4; ++i) {
      v[i] = x4[i * 256 + t];
      sm += v[i].x + v[i].y + v[i].z + v[i].w;
      am = fmaxf(am, fmaxf(fmaxf(fabsf(v[i].x), fabsf(v[i].y)),
                           fmaxf(fabsf(v[i].z), fabsf(v[i].w))));
    }
#pragma unroll
    for (int off = 32; off >= 1; off >>= 1) {
      am = fmaxf(am, __shfl_xor(am, off));
      sm += __shfl_xor(sm, off);
    }
    __shared__ float smax[4], ssum[4];
    if (lane == 0) { smax[wid] = am; ssum[wid] = sm; }
    __syncthreads();
    am = fmaxf(fmaxf(smax[0], smax[1]), fmaxf(smax[2], smax[3]));
    sm = ssum[0] + ssum[1] + ssum[2] + ssum[3];
    const float inv = am > 0.0f ? 127.0f / am : 0.0f;
    unsigned int* xo = (unsigned int*)(xq + (size_t)row * K_DIM);
#pragma unroll
    for (int i = 0; i < 4; ++i) {
      int q0 = min(127, max(-127, __float2int_rn(v[i].x * inv)));
      int q1 = min(127, max(-127, __float2int_rn(v[i].y * inv)));
      int q2 = min(127, max(-127, __float2int_rn(v[i].z * inv)));
      int q3 = min(127, max(-127, __float2int_rn(v[i].w * inv)));
      xo[i * 256 + t] = ((unsigned int)q0 & 0xFF) | (((unsigned int)q1 & 0xFF) << 8) |
                        (((unsigned int)q2 & 0xFF) << 16) | (((unsigned int)q3 & 0xFF) << 24);
    }
    if (t == 0) { r[row] = sm; sx[row] = am > 0.0f ? am / 127.0f : 0.0f; }
  } else {
    // --- repack nibbles -> q' = 2q-15 as i8 [N][K] ---
    const int total = (N_DIM * KP) / 4;  // int4 items; 4 int32 -> 8 i8
    for (int i = (b - 4096) * 256 + t; i < total; i += 4096 * 256) {
      int4 p = ((const int4*)pw)[i];
      int v[4] = {p.x, p.y, p.z, p.w};
      unsigned int u0 = 0, u1 = 0;
#pragma unroll
      for (int j = 0; j < 2; ++j) {
        unsigned int b0 = (unsigned int)(2 * (v[j] & 15) - 15) & 0xFF;
        unsigned int b1 = (unsigned int)(2 * ((v[j] >> 4) & 15) - 15) & 0xFF;
        u0 |= (b0 | (b1 << 8)) << (16 * j);
      }
#pragma unroll
      for (int j = 0; j < 2; ++j) {
        unsigned int b0 = (unsigned int)(2 * (v[2 + j] & 15) - 15) & 0xFF;
        unsigned int b1 = (unsigned int)(2 * ((v[2 + j] >> 4) & 15) - 15) & 0xFF;
        u1 |= (b0 | (b1 << 8)) << (16 * j);
      }
      uint2 st; st.x = u0; st.y = u1;
      ((uint2*)wq)[i] = st;
    }
  }
}

// ---------------- Main: 256x256 tile, BK=128 (i8), BARRIER-FREE all-register GEMM ----------------
// G'[M,N] = Xq[M,K] @ Wq[N,K]^T in i32; epilogue: out = s[o]*(0.5*sx[b]*G' + (7.5-zp[o])*r[b]).
// R17: NO LDS, NO barriers. Every wave loads its MFMA fragments directly from global
// into registers, double-buffered at half-K-tile (64 k) granularity: 12 loads issued
// one half ahead (~650 cyc lead >> L2 latency), consumed by 32 MFMA. The vmcnt FIFO
// contains ONLY register loads (R13's GLL-mixing poison cannot occur); the compiler's
// counted vmcnt(12) waits keep the pipeline 1-half deep. Serializer removed: no
// block-wide lockstep, no LDS pipe. Cost accepted: 3x L2 read traffic (192 KB/block/
// K-tile, no LDS dedup) -> new wall ~ L2 BW (~56 B/cyc/CU). Fragment addressing =
// R13's numerically-validated direct-load form for both operands. 8 waves 2M x 4N,
// wave-tile 128x64, acc 128 AGPR + ~125 VGPR -> 2 waves/SIMD.
#define BM 256
#define BN 256
#define BK 128                  // i8 elements per K-tile
#define NTILE (K_DIM / BK)      // 32
#define NT_M (M_DIM / BM)       // 16
#define NT_N (N_DIM / BN)       // 43
#define NWG  (NT_M * NT_N)      // 688 (div by 8 -> XCD swizzle bijective)

#define SCHED0   __builtin_amdgcn_sched_barrier(0)

__global__ __launch_bounds__(512, 2) void gemm_rd(const signed char* __restrict__ Xq,
                                                  const signed char* __restrict__ Wq,
                                                  const float* __restrict__ sc,
                                                  const float* __restrict__ zp,
                                                  const float* __restrict__ rbuf,
                                                  const float* __restrict__ sxbuf,
                                                  float* __restrict__ C) {
  const int t = threadIdx.x;
  const int bid = blockIdx.x;
  const int swz = (bid & 7) * (NWG / 8) + (bid >> 3);  // T1 XCD swizzle
  const int tm = swz & 15;   // M-tile
  const int tn = swz >> 4;   // N-tile (consecutive swz share the W-panel -> B L2-hot)

  // --- wave / lane geometry (8 waves = 2M x 4N, wave-tile 128x64; frozen since R7)
  const int lane = t & 63;
  const int w = t >> 6;
  const int wm = w >> 2;          // 0/1: rows wm*128..+127
  const int wn = w & 3;           // 0..3: cols wn*64..+63
  const int lr = lane & 15, lk = lane >> 4;

  // per-lane fragment byte offsets (validated direct-load form, R13 B-path):
  // A frag m: Xq[(tm*256 + wm*128 + m*16 + lr) * 4096 + KO + lk*16], 16 B
  // B frag n: Wq[(tn*256 + wn*64  + n*16 + lr) * 4096 + KO + lk*16], 16 B
  const signed char* xb = Xq + (size_t)(tm * BM) * K_DIM;
  const signed char* wb = Wq + (size_t)(tn * BN) * K_DIM;
  int aoff[8], boff[4];
#pragma unroll
  for (int m = 0; m < 8; ++m) aoff[m] = (wm * 128 + m * 16 + lr) * K_DIM + lk * 16;
#pragma unroll
  for (int n = 0; n < 4; ++n) boff[n] = (wn * 64 + n * 16 + lr) * K_DIM + lk * 16;

  i32x4 acc[8][4] = {};
  i32x4 aP[8], bP[4], aQ[8], bQ[4];   // two named half-buffers (rule #20: no runtime parity idx)

#define LOADH(A, B, KO) do {                                                    \
    _Pragma("unroll") for (int m = 0; m < 8; ++m)                               \
      A[m] = *(const i32x4*)(xb + aoff[m] + (KO));                              \
    _Pragma("unroll") for (int n = 0; n < 4; ++n)                               \
      B[n] = *(const i32x4*)(wb + boff[n] + (KO));                              \
  } while (0)

#define MFMAH(A, B) do {                                                        \
    _Pragma("unroll") for (int i = 0; i < 8; ++i)                               \
      _Pragma("unroll") for (int n = 0; n < 4; ++n)                             \
        acc[i][n] = __builtin_amdgcn_mfma_i32_16x16x64_i8(A[i], B[n], acc[i][n], 0, 0, 0); \
  } while (0)

  // prologue: half (0, kk0) in flight
  LOADH(aP, bP, 0);
  // steady state: issue next half's 12 loads, then 32 MFMA on the previous half.
  // Compiler inserts s_waitcnt vmcnt(12) before each MFMA cluster (12 newer loads in flight).
  for (int kt = 0; kt < NTILE - 1; ++kt) {
    LOADH(aQ, bQ, kt * 128 + 64);
    SCHED0;
    MFMAH(aP, bP);
    LOADH(aP, bP, kt * 128 + 128);
    SCHED0;
    MFMAH(aQ, bQ);
  }
  // tail: last kk1, drain
  LOADH(aQ, bQ, (NTILE - 1) * 128 + 64);
  SCHED0;
  MFMAH(aP, bP);
  MFMAH(aQ, bQ);

#undef LOADH
#undef MFMAH

  // epilogue: C/D layout col=lane&15, row=(lane>>4)*4+reg (dtype-independent, validated)
  const int row0 = tm * BM + wm * 128 + lk * 4;
  const int col0 = tn * BN + wn * 64 + lr;
  float sv[4], zv[4];
#pragma unroll
  for (int n = 0; n < 4; ++n) {
    sv[n] = sc[col0 + n * 16];
    zv[n] = 7.5f - zp[col0 + n * 16];
  }
#pragma unroll
  for (int m = 0; m < 8; ++m)
#pragma unroll
    for (int rr = 0; rr < 4; ++rr) {
      const int row = row0 + m * 16 + rr;
      const float rv = rbuf[row];
      const float hx = 0.5f * sxbuf[row];
#pragma unroll
      for (int n = 0; n < 4; ++n)
        C[(size_t)row * N_DIM + col0 + n * 16] = sv[n] * (hx * (float)acc[m][n][rr] + zv[n] * rv);
    }
}

// ---------------- Fallback: fp32 LDS-tiled GEMM reading packed weights (ws too small) ----------------
__global__ __launch_bounds__(256) void fallback_gemm(const float* __restrict__ x,
                                                     const int* __restrict__ pw,
                                                     const float* __restrict__ sc,
                                                     const float* __restrict__ zp,
                                                     float* __restrict__ out) {
  __shared__ float Xs[64][33];
  __shared__ float Ws[64][33];
  const int bid = blockIdx.x;
  const int bm = bid & 63;
  const int bn = bid >> 6;
  const int t = threadIdx.x;
  const int tx = t & 15, ty = t >> 4;
  float acc[4][4] = {};
  for (int k0 = 0; k0 < K_DIM; k0 += 32) {
    __syncthreads();
#pragma unroll
    for (int i = 0; i < 8; ++i) {
      int e = t + i * 256; int rr = e >> 5, c = e & 31;
      Xs[rr][c] = x[(size_t)(bm * 64 + rr) * K_DIM + k0 + c];
    }
#pragma unroll
    for (int i = 0; i < 4; ++i) {
      int e = t + i * 256; int rr = e >> 4, jj = e & 15;
      int row = bn * 64 + rr;
      int v = pw[(size_t)row * KP + (k0 >> 1) + jj];
      float s = sc[row], z = zp[row];
      Ws[rr][2 * jj]     = ((float)(v & 15) - z) * s;
      Ws[rr][2 * jj + 1] = ((float)((v >> 4) & 15) - z) * s;
    }
    __syncthreads();
#pragma unroll
    for (int kk = 0; kk < 32; ++kk) {
      float a[4], b[4];
#pragma unroll
      for (int i2 = 0; i2 < 4; ++i2) a[i2] = Xs[ty * 4 + i2][kk];
#pragma unroll
      for (int j2 = 0; j2 < 4; ++j2) b[j2] = Ws[tx * 4 + j2][kk];
#pragma unroll
      for (int i2 = 0; i2 < 4; ++i2)
#pragma unroll
        for (int j2 = 0; j2 < 4; ++j2) acc[i2][j2] += a[i2] * b[j2];
    }
  }
#pragma unroll
  for (int i2 = 0; i2 < 4; ++i2)
#pragma unroll
    for (int j2 = 0; j2 < 4; ++j2)
      out[(size_t)(bm * 64 + ty * 4 + i2) * N_DIM + bn * 64 + tx * 4 + j2] = acc[i2][j2];
}

extern "C" void kernel_launch(void* const* d_in, const int* in_sizes, int n_in,
                              void* d_out, int out_size, void* d_ws, size_t ws_size,
                              hipStream_t stream) {
  const float* x  = (const float*)d_in[0];
  const int*   pw = (const int*)d_in[1];
  const float* sc = (const float*)d_in[2];
  const float* zp = (const float*)d_in[3];
  float* out = (float*)d_out;

  const size_t wq_b = (size_t)N_DIM * K_DIM;   // 45,088,768
  const size_t xq_b = (size_t)M_DIM * K_DIM;   // 16,777,216
  const size_t need = wq_b + xq_b + 2 * 4096 * sizeof(float);

  if (ws_size >= need) {
    signed char* wq = (signed char*)d_ws;
    signed char* xq = wq + wq_b;
    float* rbuf  = (float*)((char*)d_ws + wq_b + xq_b);
    float* sxbuf = rbuf + 4096;
    hipLaunchKernelGGL(prep,    dim3(4096 + 4096), dim3(256), 0, stream, x, pw, xq, wq, rbuf, sxbuf);
    hipLaunchKernelGGL(gemm_rd, dim3(NWG),         dim3(512), 0, stream, xq, wq, sc, zp, rbuf, sxbuf, out);
  } else {
    hipLaunchKernelGGL(fallback_gemm, dim3(64 * 172), dim3(256), 0, stream, x, pw, sc, zp, out);
  }
}

// Round 18
// 216.266 us; speedup vs baseline: 3.0323x; 3.0323x over previous
//
#include <hip/hip_runtime.h>
#include <hip/hip_bf16.h>
#include <stdint.h>

#define M_DIM 4096
#define N_DIM 11008
#define K_DIM 4096
#define KP    (K_DIM / 2)   // packed int32s per weight row

typedef __attribute__((ext_vector_type(4))) int i32x4;

#define AS1 __attribute__((address_space(1)))
#define AS3 __attribute__((address_space(3)))

// ---------------- Fused pre-pass: quant_x (blocks 0..4095) + pack_q (blocks 4096..8191) ----------------
__global__ __launch_bounds__(256) void prep(const float* __restrict__ x,
                                            const int* __restrict__ pw,
                                            signed char* __restrict__ xq,
                                            signed char* __restrict__ wq,
                                            float* __restrict__ r,
                                            float* __restrict__ sx) {
  const int b = blockIdx.x;
  const int t = threadIdx.x;
  if (b < 4096) {
    // --- per-row quantize x -> i8, emit r[b]=sum(x), sx[b]=scale ---
    const int row = b;
    const int lane = t & 63, wid = t >> 6;
    const float4* x4 = (const float4*)(x + (size_t)row * K_DIM);
    float4 v[4];
    float am = 0.0f, sm = 0.0f;
#pragma unroll
    for (int i = 0; i < 4; ++i) {
      v[i] = x4[i * 256 + t];
      sm += v[i].x + v[i].y + v[i].z + v[i].w;
      am = fmaxf(am, fmaxf(fmaxf(fabsf(v[i].x), fabsf(v[i].y)),
                           fmaxf(fabsf(v[i].z), fabsf(v[i].w))));
    }
#pragma unroll
    for (int off = 32; off >= 1; off >>= 1) {
      am = fmaxf(am, __shfl_xor(am, off));
      sm += __shfl_xor(sm, off);
    }
    __shared__ float smax[4], ssum[4];
    if (lane == 0) { smax[wid] = am; ssum[wid] = sm; }
    __syncthreads();
    am = fmaxf(fmaxf(smax[0], smax[1]), fmaxf(smax[2], smax[3]));
    sm = ssum[0] + ssum[1] + ssum[2] + ssum[3];
    const float inv = am > 0.0f ? 127.0f / am : 0.0f;
    unsigned int* xo = (unsigned int*)(xq + (size_t)row * K_DIM);
#pragma unroll
    for (int i = 0; i < 4; ++i) {
      int q0 = min(127, max(-127, __float2int_rn(v[i].x * inv)));
      int q1 = min(127, max(-127, __float2int_rn(v[i].y * inv)));
      int q2 = min(127, max(-127, __float2int_rn(v[i].z * inv)));
      int q3 = min(127, max(-127, __float2int_rn(v[i].w * inv)));
      xo[i * 256 + t] = ((unsigned int)q0 & 0xFF) | (((unsigned int)q1 & 0xFF) << 8) |
                        (((unsigned int)q2 & 0xFF) << 16) | (((unsigned int)q3 & 0xFF) << 24);
    }
    if (t == 0) { r[row] = sm; sx[row] = am > 0.0f ? am / 127.0f : 0.0f; }
  } else {
    // --- repack nibbles -> q' = 2q-15 as i8 [N][K] ---
    const int total = (N_DIM * KP) / 4;  // int4 items; 4 int32 -> 8 i8
    for (int i = (b - 4096) * 256 + t; i < total; i += 4096 * 256) {
      int4 p = ((const int4*)pw)[i];
      int v[4] = {p.x, p.y, p.z, p.w};
      unsigned int u0 = 0, u1 = 0;
#pragma unroll
      for (int j = 0; j < 2; ++j) {
        unsigned int b0 = (unsigned int)(2 * (v[j] & 15) - 15) & 0xFF;
        unsigned int b1 = (unsigned int)(2 * ((v[j] >> 4) & 15) - 15) & 0xFF;
        u0 |= (b0 | (b1 << 8)) << (16 * j);
      }
#pragma unroll
      for (int j = 0; j < 2; ++j) {
        unsigned int b0 = (unsigned int)(2 * (v[2 + j] & 15) - 15) & 0xFF;
        unsigned int b1 = (unsigned int)(2 * ((v[2 + j] >> 4) & 15) - 15) & 0xFF;
        u1 |= (b0 | (b1 << 8)) << (16 * j);
      }
      uint2 st; st.x = u0; st.y = u1;
      ((uint2*)wq)[i] = st;
    }
  }
}

// ---------------- Main: 256x256 tile, BK=128 (i8), pipelined i8 MFMA GEMM (R11/R14 config, proven best) ----------------
// G'[M,N] = Xq[M,K] @ Wq[N,K]^T in i32; epilogue: out = s[o]*(0.5*sx[b]*G' + (7.5-zp[o])*r[b]).
// Final consolidated structure. Proven components: i8 exact-weight factorized quant GEMM
// (R7: halves bytes/FLOP, W exact), 128B-row XOR-swizzled LDS (0 conflicts R7-R16),
// linear GLL dst + pre-swizzled global src (m104/m173), counted vmcnt(4) once per K-tile,
// barrier-diet 2 fences/K-tile (R6), phase-pipelined reads w/ SCHED0 (R10), NO setprio
// (R11: +7%), XCD-bijective swizzle (T1), balanced fused prep (R14).
// Doors closed by measurement: R5 hoist (reg cliff), R8 small tile (bank math), R12
// 16-wave (same barrier group), R13 B-direct (scattered-request latency), R15 fence
// removal (null), R17 all-register barrier-free (L2 request-rate wall, -3.7x).
// Residual gap to i8 ceiling (47% MfmaUtil) = HIP-source schedule limit for this class.
#define BM 256
#define BN 256
#define BK 128                  // i8 elements per K-tile
#define NTILE (K_DIM / BK)      // 32
#define NT_M (M_DIM / BM)       // 16
#define NT_N (N_DIM / BN)       // 43
#define NWG  (NT_M * NT_N)      // 688 (div by 8 -> XCD swizzle bijective)
#define HS 16384                // half-slot bytes
#define PS 65536                // parity stride (4 half-slots)

#define WAITV(n) asm volatile("s_waitcnt vmcnt(" #n ")" ::: "memory")
#define WAITL0   asm volatile("s_waitcnt lgkmcnt(0)" ::: "memory")
#define BARR     do { asm volatile("" ::: "memory"); __builtin_amdgcn_s_barrier(); asm volatile("" ::: "memory"); } while (0)
#define SCHED0   __builtin_amdgcn_sched_barrier(0)

__global__ __launch_bounds__(512, 2) void gemm_i8(const signed char* __restrict__ Xq,
                                                  const signed char* __restrict__ Wq,
                                                  const float* __restrict__ sc,
                                                  const float* __restrict__ zp,
                                                  const float* __restrict__ rbuf,
                                                  const float* __restrict__ sxbuf,
                                                  float* __restrict__ C) {
  __shared__ __align__(16) unsigned char lds8[131072];  // 128 KiB

  const int t = threadIdx.x;
  const int bid = blockIdx.x;
  const int swz = (bid & 7) * (NWG / 8) + (bid >> 3);  // T1 XCD swizzle
  const int tm = swz & 15;   // M-tile
  const int tn = swz >> 4;   // N-tile

  // --- stage sources: thread t owns LDS chunks c0=t (rows 0..63) and c1=t+512 (rows 64..127).
  // chunk c: row = c>>3, slot j = c&7, global chunk g = j ^ (row&7); 16 B per chunk.
  const int srow = t >> 3;
  const int g0 = (t & 7) ^ (srow & 7);
  const int koff = g0 * 16;                      // BYTE offset within K-tile
  const signed char* pB0c0 = Wq + (size_t)(tn * BN + srow) * K_DIM + koff;
  const signed char* pB0c1 = Wq + (size_t)(tn * BN + 64 + srow) * K_DIM + koff;
  const signed char* pB1c0 = Wq + (size_t)(tn * BN + 128 + srow) * K_DIM + koff;
  const signed char* pB1c1 = Wq + (size_t)(tn * BN + 192 + srow) * K_DIM + koff;
  const signed char* pA0c0 = Xq + (size_t)(tm * BM + srow) * K_DIM + koff;
  const signed char* pA0c1 = Xq + (size_t)(tm * BM + 64 + srow) * K_DIM + koff;
  const signed char* pA1c0 = Xq + (size_t)(tm * BM + 128 + srow) * K_DIM + koff;
  const signed char* pA1c1 = Xq + (size_t)(tm * BM + 192 + srow) * K_DIM + koff;
  const int d0 = t * 16;           // linear LDS byte offset of chunk c0 (m104 rule)
  const int d1 = d0 + 8192;        // chunk c1

  // --- wave / lane geometry
  const int lane = t & 63;
  const int w = t >> 6;
  const int wm = w >> 2;          // A-half
  const int wn = w & 3;           // B col group; B-half = wn>>1
  const int lr = lane & 15, lk = lane >> 4;

  // fragment read bases (BYTES). row stride 128 B; frag (row=16m+lr, chunk g=ks*4+lk)
  // at slot j = g ^ (lr&7); ks=1 flips chunk bit2 -> addr ^ 64.
  const int j0 = lk ^ (lr & 7);
  const int aB0 = (2 + wm) * HS + lr * 128 + j0 * 16;
  const int aB1 = aB0 ^ 64;
  const int bB0 = (wn >> 1) * HS + (wn & 1) * 8192 + lr * 128 + j0 * 16;
  const int bB1 = bB0 ^ 64;

  i32x4 acc[8][4] = {};

#define GLL(src, dstoff) \
  __builtin_amdgcn_global_load_lds((const AS1 void*)(src), (AS3 void*)(lds8 + (dstoff)), 16, 0, 0)

  // ---- prologue: stage B0,B1,A0,A1 of tile0 (parity0), B0,B1 of tile1 (parity1)
  GLL(pB0c0, 0 * HS + d0); GLL(pB0c1, 0 * HS + d1);
  GLL(pB1c0, 1 * HS + d0); GLL(pB1c1, 1 * HS + d1);
  GLL(pA0c0, 2 * HS + d0); GLL(pA0c1, 2 * HS + d1);
  GLL(pA1c0, 3 * HS + d0); GLL(pA1c1, 3 * HS + d1);
  GLL(pB0c0 + BK, 4 * HS + d0); GLL(pB0c1 + BK, 4 * HS + d1);
  GLL(pB1c0 + BK, 5 * HS + d0); GLL(pB1c1 + BK, 5 * HS + d1);
  pB0c0 += 2 * BK; pB0c1 += 2 * BK; pB1c0 += 2 * BK; pB1c1 += 2 * BK;
  pA0c0 += BK;     pA0c1 += BK;     pA1c0 += BK;     pA1c1 += BK;
  WAITV(4);  // tile0 resident; B(tile1) in flight
  BARR;

  // VMODE: 0 -> vmcnt(4), 1 -> vmcnt(0), 2 -> none
#define TILE(P, SA, SB, VMODE) do {                                                        \
    i32x4 a0[4], a1[4], a2[4], a3[4], b0[4], b1[4];                                        \
    /* ---- P1: issue reads a0,b0 AND a1; stage A0(t+1); MFMA a0 x b0 ---- */              \
    _Pragma("unroll") for (int i = 0; i < 4; ++i)                                          \
      a0[i] = *(const i32x4*)(lds8 + (P) * PS + aB0 + i * 2048);                           \
    _Pragma("unroll") for (int n = 0; n < 4; ++n)                                          \
      b0[n] = *(const i32x4*)(lds8 + (P) * PS + bB0 + n * 2048);                           \
    _Pragma("unroll") for (int i = 0; i < 4; ++i)                                          \
      a1[i] = *(const i32x4*)(lds8 + (P) * PS + aB0 + (4 + i) * 2048);                     \
    if (SA) { GLL(pA0c0, (((P) ^ 1) * 4 + 2) * HS + d0);                                   \
              GLL(pA0c1, (((P) ^ 1) * 4 + 2) * HS + d1);                                   \
              pA0c0 += BK; pA0c1 += BK; }                                                  \
    SCHED0;                                                                                \
    _Pragma("unroll") for (int i = 0; i < 4; ++i)                                          \
      _Pragma("unroll") for (int n = 0; n < 4; ++n)                                        \
        acc[i][n] = __builtin_amdgcn_mfma_i32_16x16x64_i8(a0[i], b0[n], acc[i][n], 0, 0, 0); \
    /* ---- P2: issue reads b1,a2; stage A1(t+1); MFMA a1 x b0; lgkm0; MID BARRIER ---- */ \
    _Pragma("unroll") for (int n = 0; n < 4; ++n)                                          \
      b1[n] = *(const i32x4*)(lds8 + (P) * PS + bB1 + n * 2048);                           \
    _Pragma("unroll") for (int i = 0; i < 4; ++i)                                          \
      a2[i] = *(const i32x4*)(lds8 + (P) * PS + aB1 + i * 2048);                           \
    if (SA) { GLL(pA1c0, (((P) ^ 1) * 4 + 3) * HS + d0);                                   \
              GLL(pA1c1, (((P) ^ 1) * 4 + 3) * HS + d1);                                   \
              pA1c0 += BK; pA1c1 += BK; }                                                  \
    SCHED0;                                                                                \
    _Pragma("unroll") for (int i = 0; i < 4; ++i)                                          \
      _Pragma("unroll") for (int n = 0; n < 4; ++n)                                        \
        acc[4 + i][n] = __builtin_amdgcn_mfma_i32_16x16x64_i8(a1[i], b0[n], acc[4 + i][n], 0, 0, 0); \
    WAITL0;                                                                                \
    BARR;                                                                                  \
    /* ---- P3: issue reads a3; stage B0(t+2); MFMA a2 x b1 ---- */                        \
    _Pragma("unroll") for (int i = 0; i < 4; ++i)                                          \
      a3[i] = *(const i32x4*)(lds8 + (P) * PS + aB1 + (4 + i) * 2048);                     \
    if (SB) { GLL(pB0c0, ((P) * 4 + 0) * HS + d0);                                         \
              GLL(pB0c1, ((P) * 4 + 0) * HS + d1);                                         \
              pB0c0 += BK; pB0c1 += BK; }                                                  \
    SCHED0;                                                                                \
    _Pragma("unroll") for (int i = 0; i < 4; ++i)                                          \
      _Pragma("unroll") for (int n = 0; n < 4; ++n)                                        \
        acc[i][n] = __builtin_amdgcn_mfma_i32_16x16x64_i8(a2[i], b1[n], acc[i][n], 0, 0, 0); \
    /* ---- P4: stage B1(t+2); MFMA a3 x b1; WAITV; END BARRIER ---- */                    \
    if (SB) { GLL(pB1c0, ((P) * 4 + 1) * HS + d0);                                         \
              GLL(pB1c1, ((P) * 4 + 1) * HS + d1);                                         \
              pB1c0 += BK; pB1c1 += BK; }                                                  \
    SCHED0;                                                                                \
    _Pragma("unroll") for (int i = 0; i < 4; ++i)                                          \
      _Pragma("unroll") for (int n = 0; n < 4; ++n)                                        \
        acc[4 + i][n] = __builtin_amdgcn_mfma_i32_16x16x64_i8(a3[i], b1[n], acc[4 + i][n], 0, 0, 0); \
    if ((VMODE) == 0) { WAITV(4); } else if ((VMODE) == 1) { WAITV(0); }                   \
    BARR;                                                                                  \
  } while (0)

  // main loop: tiles 0..29
  for (int it = 0; it < (NTILE - 2) / 2; ++it) {
    TILE(0, 1, 1, 0);
    TILE(1, 1, 1, 0);
  }
  TILE(0, 1, 0, 1);   // tile 30: stage A(31) only; drain
  TILE(1, 0, 0, 2);   // tile 31: no stage, no wait

#undef TILE
#undef GLL

  // epilogue: C/D layout col=lane&15, row=(lane>>4)*4+reg (dtype-independent, validated)
  const int row0 = tm * BM + wm * 128 + lk * 4;
  const int col0 = tn * BN + wn * 64 + lr;
  float sv[4], zv[4];
#pragma unroll
  for (int n = 0; n < 4; ++n) {
    sv[n] = sc[col0 + n * 16];
    zv[n] = 7.5f - zp[col0 + n * 16];
  }
#pragma unroll
  for (int m = 0; m < 8; ++m)
#pragma unroll
    for (int rr = 0; rr < 4; ++rr) {
      const int row = row0 + m * 16 + rr;
      const float rv = rbuf[row];
      const float hx = 0.5f * sxbuf[row];
#pragma unroll
      for (int n = 0; n < 4; ++n)
        C[(size_t)row * N_DIM + col0 + n * 16] = sv[n] * (hx * (float)acc[m][n][rr] + zv[n] * rv);
    }
}

// ---------------- Fallback: fp32 LDS-tiled GEMM reading packed weights (ws too small) ----------------
__global__ __launch_bounds__(256) void fallback_gemm(const float* __restrict__ x,
                                                     const int* __restrict__ pw,
                                                     const float* __restrict__ sc,
                                                     const float* __restrict__ zp,
                                                     float* __restrict__ out) {
  __shared__ float Xs[64][33];
  __shared__ float Ws[64][33];
  const int bid = blockIdx.x;
  const int bm = bid & 63;
  const int bn = bid >> 6;
  const int t = threadIdx.x;
  const int tx = t & 15, ty = t >> 4;
  float acc[4][4] = {};
  for (int k0 = 0; k0 < K_DIM; k0 += 32) {
    __syncthreads();
#pragma unroll
    for (int i = 0; i < 8; ++i) {
      int e = t + i * 256; int rr = e >> 5, c = e & 31;
      Xs[rr][c] = x[(size_t)(bm * 64 + rr) * K_DIM + k0 + c];
    }
#pragma unroll
    for (int i = 0; i < 4; ++i) {
      int e = t + i * 256; int rr = e >> 4, jj = e & 15;
      int row = bn * 64 + rr;
      int v = pw[(size_t)row * KP + (k0 >> 1) + jj];
      float s = sc[row], z = zp[row];
      Ws[rr][2 * jj]     = ((float)(v & 15) - z) * s;
      Ws[rr][2 * jj + 1] = ((float)((v >> 4) & 15) - z) * s;
    }
    __syncthreads();
#pragma unroll
    for (int kk = 0; kk < 32; ++kk) {
      float a[4], b[4];
#pragma unroll
      for (int i2 = 0; i2 < 4; ++i2) a[i2] = Xs[ty * 4 + i2][kk];
#pragma unroll
      for (int j2 = 0; j2 < 4; ++j2) b[j2] = Ws[tx * 4 + j2][kk];
#pragma unroll
      for (int i2 = 0; i2 < 4; ++i2)
#pragma unroll
        for (int j2 = 0; j2 < 4; ++j2) acc[i2][j2] += a[i2] * b[j2];
    }
  }
#pragma unroll
  for (int i2 = 0; i2 < 4; ++i2)
#pragma unroll
    for (int j2 = 0; j2 < 4; ++j2)
      out[(size_t)(bm * 64 + ty * 4 + i2) * N_DIM + bn * 64 + tx * 4 + j2] = acc[i2][j2];
}

extern "C" void kernel_launch(void* const* d_in, const int* in_sizes, int n_in,
                              void* d_out, int out_size, void* d_ws, size_t ws_size,
                              hipStream_t stream) {
  const float* x  = (const float*)d_in[0];
  const int*   pw = (const int*)d_in[1];
  const float* sc = (const float*)d_in[2];
  const float* zp = (const float*)d_in[3];
  float* out = (float*)d_out;

  const size_t wq_b = (size_t)N_DIM * K_DIM;   // 45,088,768
  const size_t xq_b = (size_t)M_DIM * K_DIM;   // 16,777,216
  const size_t need = wq_b + xq_b + 2 * 4096 * sizeof(float);

  if (ws_size >= need) {
    signed char* wq = (signed char*)d_ws;
    signed char* xq = wq + wq_b;
    float* rbuf  = (float*)((char*)d_ws + wq_b + xq_b);
    float* sxbuf = rbuf + 4096;
    hipLaunchKernelGGL(prep,    dim3(4096 + 4096), dim3(256), 0, stream, x, pw, xq, wq, rbuf, sxbuf);
    hipLaunchKernelGGL(gemm_i8, dim3(NWG),         dim3(512), 0, stream, xq, wq, sc, zp, rbuf, sxbuf, out);
  } else {
    hipLaunchKernelGGL(fallback_gemm, dim3(64 * 172), dim3(256), 0, stream, x, pw, sc, zp, out);
  }
}